// Round 6
// baseline (1333.557 us; speedup 1.0000x reference)
//
#include <hip/hip_runtime.h>

// LightGCN: out = 0.25*(e0 + S e0 + S^2 e0 + S^3 e0), S = 10M-nnz COO, N=500k, EMB=64.
// R7: two-pass aggregated scatter. 1849.7 us.
// R8: column-split: regressed (gather miss ~50% invariant -> fabric-bytes bound).
// R9: bf16 gather tables: spmm 430.9 -> 266 us/layer (FETCH 1.50GB -> 871MB). 1324.6 us.
//   spmm now at fabric roofline (~6 TB/s L2-miss bytes). Remaining: ~525 us preprocessing,
//   of which scatter_sb + finalize_sb ~ 494 us vs ~65 us BW-ideal. Suspects: per-address
//   global-atomic serialization (1396 RMW per cursor[sb]) and finalize's 8B-scatter
//   L2 write-window thrash (10MB active / 4MB L2 per XCD).
// R10: deterministic two-level scan preprocessing:
//   tile_hist: per-tile per-SB counts -> cnt[t][sb] (coalesced row writes, no atomics).
//   col_base:  per-SB column walk converts counts -> exact global bases (prefetch-8).
//   scatter_sb: stages tile sorted by SB in LDS (sbid array, no binary search), writes
//     runs at deterministic bases. ZERO global atomics.
//   finalize_sb: SB=512 rows; sorts in LDS out[] staging (100KB) and writes back
//     SEQUENTIALLY (no L2 thrash).
// Horner (bfA=e0_bf16, bfB scratch, W=d_out f32):
//   L1: bfB = bf16(e0 + S bfA); L2: bfA = bf16(e0 + S bfB); L3: W = 0.25f32(e0 + S bfA).

#define NUSERS 100000
#define NNODES 500000
#define EMB 64
#define COLBITS 19
#define CMASK ((1u << COLBITS) - 1u)

#define SBBITS 9                                   // 512 rows per super-bucket
#define SBROWS (1 << SBBITS)
#define SBMASK (SBROWS - 1)
#define NSB ((NNODES + SBROWS - 1) / SBROWS)       // 977
#define TILE 7168                                  // pairs staged per block in pass 1
#define P2_THREADS 512
#define P2_CAP 12800                               // LDS staging cap (mean 10240, sd ~101)
#define P2_K 25                                    // ceil(P2_CAP / P2_THREADS)
#define SLACK_PAIRS 262144                         // pass-2 overflow staging (never hit)

typedef unsigned long long ull;

// f32 pair -> packed bf16x2 (round-to-nearest-even)
__device__ __forceinline__ unsigned pk2(float lo, float hi) {
  unsigned a = __float_as_uint(lo);
  unsigned b = __float_as_uint(hi);
  a = (a + 0x7fffu + ((a >> 16) & 1u)) >> 16;
  b = (b + 0x7fffu + ((b >> 16) & 1u)) & 0xffff0000u;
  return (a & 0xffffu) | b;
}
__device__ __forceinline__ float blo(unsigned u) { return __uint_as_float(u << 16); }
__device__ __forceinline__ float bhi(unsigned u) { return __uint_as_float(u & 0xffff0000u); }

// ---------------- preprocessing ----------------

// Global per-SB histogram (for bptr scan). LDS-combined, 256 blocks.
__global__ void hist_sb(const int* __restrict__ rows, int nnz,
                        int* __restrict__ counts) {
  __shared__ int h[NSB];
  for (int i = threadIdx.x; i < NSB; i += blockDim.x) h[i] = 0;
  __syncthreads();
  int i = blockIdx.x * blockDim.x + threadIdx.x;
  int stride = gridDim.x * blockDim.x;
  for (; i < nnz; i += stride) atomicAdd(&h[rows[i] >> SBBITS], 1);
  __syncthreads();
  for (int j = threadIdx.x; j < NSB; j += blockDim.x)
    if (h[j]) atomicAdd(&counts[j], h[j]);
}

// Single-block exclusive scan of counts[n] (n <= 4096), 512 threads x 8.
__global__ void scan_buckets(const int* __restrict__ counts,
                             int* __restrict__ bptr, int* __restrict__ cursor,
                             int n, int nnz) {
  __shared__ int s[512];
  const int t = threadIdx.x;
  const int base = t * 8;
  int e[8];
  int tsum = 0;
#pragma unroll
  for (int j = 0; j < 8; ++j) {
    e[j] = (base + j < n) ? counts[base + j] : 0;
    tsum += e[j];
  }
  s[t] = tsum;
  __syncthreads();
  for (int off = 1; off < 512; off <<= 1) {
    int v = (t >= off) ? s[t - off] : 0;
    __syncthreads();
    s[t] += v;
    __syncthreads();
  }
  int run = s[t] - tsum;
#pragma unroll
  for (int j = 0; j < 8; ++j) {
    if (base + j < n) { bptr[base + j] = run; cursor[base + j] = run; }
    run += e[j];
  }
  if (t == 511) bptr[n] = nnz;
}

// Per-tile per-SB histogram -> cnt[t * NSB + sb] (coalesced row writes, no global atomics).
__global__ __launch_bounds__(256) void tile_hist(const int* __restrict__ rows, int nnz,
                                                 int* __restrict__ cntmat) {
  __shared__ int h[NSB];
  const int t = threadIdx.x;
  const int tile0 = blockIdx.x * TILE;
  const int tileN = min(TILE, nnz - tile0);
  if (tileN <= 0) return;
  for (int i = t; i < NSB; i += 256) h[i] = 0;
  __syncthreads();
  for (int i = t; i < tileN; i += 256) atomicAdd(&h[rows[tile0 + i] >> SBBITS], 1);
  __syncthreads();
  int* row = cntmat + (size_t)blockIdx.x * NSB;
  for (int i = t; i < NSB; i += 256) row[i] = h[i];
}

// Convert per-tile counts into exact global bases, in place:
// A[t][sb] := bptr[sb] + sum_{t'<t} A[t'][sb].  One thread per SB column,
// software-pipelined depth-8 (loads coalesced across the 64 lanes of a wave).
__global__ void col_base(int* __restrict__ A, int ntiles,
                         const int* __restrict__ bptr) {
  int sb = blockIdx.x * 64 + threadIdx.x;
  if (sb >= NSB) return;
  int run = bptr[sb];
  int t = 0;
  if (ntiles >= 16) {
    int b0 = A[(size_t)0 * NSB + sb], b1 = A[(size_t)1 * NSB + sb];
    int b2 = A[(size_t)2 * NSB + sb], b3 = A[(size_t)3 * NSB + sb];
    int b4 = A[(size_t)4 * NSB + sb], b5 = A[(size_t)5 * NSB + sb];
    int b6 = A[(size_t)6 * NSB + sb], b7 = A[(size_t)7 * NSB + sb];
    for (; t + 16 <= ntiles; t += 8) {
      int n0 = A[(size_t)(t + 8) * NSB + sb],  n1 = A[(size_t)(t + 9) * NSB + sb];
      int n2 = A[(size_t)(t + 10) * NSB + sb], n3 = A[(size_t)(t + 11) * NSB + sb];
      int n4 = A[(size_t)(t + 12) * NSB + sb], n5 = A[(size_t)(t + 13) * NSB + sb];
      int n6 = A[(size_t)(t + 14) * NSB + sb], n7 = A[(size_t)(t + 15) * NSB + sb];
      A[(size_t)(t + 0) * NSB + sb] = run; run += b0;
      A[(size_t)(t + 1) * NSB + sb] = run; run += b1;
      A[(size_t)(t + 2) * NSB + sb] = run; run += b2;
      A[(size_t)(t + 3) * NSB + sb] = run; run += b3;
      A[(size_t)(t + 4) * NSB + sb] = run; run += b4;
      A[(size_t)(t + 5) * NSB + sb] = run; run += b5;
      A[(size_t)(t + 6) * NSB + sb] = run; run += b6;
      A[(size_t)(t + 7) * NSB + sb] = run; run += b7;
      b0 = n0; b1 = n1; b2 = n2; b3 = n3;
      b4 = n4; b5 = n5; b6 = n6; b7 = n7;
    }
    A[(size_t)(t + 0) * NSB + sb] = run; run += b0;
    A[(size_t)(t + 1) * NSB + sb] = run; run += b1;
    A[(size_t)(t + 2) * NSB + sb] = run; run += b2;
    A[(size_t)(t + 3) * NSB + sb] = run; run += b3;
    A[(size_t)(t + 4) * NSB + sb] = run; run += b4;
    A[(size_t)(t + 5) * NSB + sb] = run; run += b5;
    A[(size_t)(t + 6) * NSB + sb] = run; run += b6;
    A[(size_t)(t + 7) * NSB + sb] = run; run += b7;
    t += 8;
  }
  for (; t < ntiles; ++t) {
    size_t i = (size_t)t * NSB + sb;
    int c = A[i];
    A[i] = run;
    run += c;
  }
}

// Pass 1: LDS-aggregated scatter into NSB super-bucket regions at deterministic
// bases (no global atomics). key = (row&511)<<19 | col, val alongside.
__global__ __launch_bounds__(256) void scatter_sb(
    const int* __restrict__ rows, const int* __restrict__ cols,
    const float* __restrict__ vals, int nnz,
    const int* __restrict__ basemat, ull* __restrict__ pairs) {
  __shared__ ull stg[TILE];                    // 56 KiB
  __shared__ ushort sbid[TILE];                // 14 KiB
  __shared__ int cnt[NSB];                     // 3.9 KiB
  __shared__ int start[NSB];                   // 3.9 KiB
  __shared__ int ssc[256];                     // 1 KiB
  const int t = threadIdx.x;
  const int tile0 = blockIdx.x * TILE;
  const int tileN = min(TILE, nnz - tile0);
  if (tileN <= 0) return;

  for (int i = t; i < NSB; i += 256) cnt[i] = 0;
  __syncthreads();

  // phase A: read rows, histogram by SB (rows kept in registers)
  int rr[TILE / 256];
#pragma unroll
  for (int k = 0; k < TILE / 256; ++k) {
    int idx = tile0 + t + k * 256;
    rr[k] = (idx < nnz) ? rows[idx] : -1;
    if (rr[k] >= 0) atomicAdd(&cnt[rr[k] >> SBBITS], 1);
  }
  __syncthreads();

  // exclusive scan of cnt -> start (4 entries/thread, Hillis-Steele over 256)
  {
    int c[4];
    int tsum = 0;
#pragma unroll
    for (int j = 0; j < 4; ++j) {
      int i = t * 4 + j;
      c[j] = (i < NSB) ? cnt[i] : 0;
      tsum += c[j];
    }
    ssc[t] = tsum;
    __syncthreads();
    for (int off = 1; off < 256; off <<= 1) {
      int v = (t >= off) ? ssc[t - off] : 0;
      __syncthreads();
      ssc[t] += v;
      __syncthreads();
    }
    int run = ssc[t] - tsum;
#pragma unroll
    for (int j = 0; j < 4; ++j) {
      int i = t * 4 + j;
      if (i < NSB) start[i] = run;
      run += c[j];
    }
  }
  __syncthreads();
  for (int i = t; i < NSB; i += 256) cnt[i] = 0;
  __syncthreads();

  // phase B: read cols/vals, stage pairs grouped by SB in LDS (+ sbid tag)
#pragma unroll
  for (int k = 0; k < TILE / 256; ++k) {
    int idx = tile0 + t + k * 256;
    if (idx < nnz) {
      int r = rr[k];
      int sb = r >> SBBITS;
      unsigned key = ((unsigned)(r & SBMASK) << COLBITS) | (unsigned)cols[idx];
      ull p = ((ull)__float_as_uint(vals[idx]) << 32) | key;
      int j = start[sb] + atomicAdd(&cnt[sb], 1);
      stg[j] = p;
      sbid[j] = (ushort)sb;
    }
  }
  __syncthreads();

  // phase C: write staged pairs to deterministic global bases; consecutive j ->
  // same SB -> coalesced runs.
  const int* __restrict__ baserow = basemat + (size_t)blockIdx.x * NSB;
  for (int j = t; j < tileN; j += 256) {
    int sb = sbid[j];
    pairs[baserow[sb] + (j - start[sb])] = stg[j];
  }
}

// Pass 2: per-SB row grouping. Loads region into registers, counting sort by row,
// stages sorted result in LDS, writes back SEQUENTIALLY. rs/re per row.
__global__ __launch_bounds__(P2_THREADS) void finalize_sb(
    const int* __restrict__ bptr, ull* __restrict__ pairs,
    int* __restrict__ rs, int* __restrict__ re,
    int* __restrict__ ovf_alloc, int nnz) {
  __shared__ int hist[SBROWS];
  __shared__ int start[SBROWS];
  __shared__ int cur[SBROWS];
  __shared__ ull out[P2_CAP];                  // 100 KiB
  __shared__ int ovf_base;
  const int b = blockIdx.x;
  const int t = threadIdx.x;
  const int s = bptr[b];
  const int n = bptr[b + 1] - s;
  const bool ovf = (n > P2_CAP);

  hist[t] = 0;
  ull* __restrict__ slack = pairs + nnz;
  if (ovf && t == 0) ovf_base = atomicAdd(ovf_alloc, n);
  __syncthreads();

  ull q[P2_K];
  if (!ovf) {
#pragma unroll
    for (int k = 0; k < P2_K; ++k) {
      int idx = t + k * P2_THREADS;
      if (idx < n) {
        q[k] = pairs[s + idx];
        atomicAdd(&hist[(unsigned)q[k] >> COLBITS], 1);
      }
    }
  } else {
    for (int j = t; j < n; j += P2_THREADS) slack[ovf_base + j] = pairs[s + j];
    __syncthreads();
    for (int j = t; j < n; j += P2_THREADS)
      atomicAdd(&hist[(unsigned)slack[ovf_base + j] >> COLBITS], 1);
  }
  __syncthreads();

  start[t] = hist[t];
  __syncthreads();
  for (int off = 1; off < SBROWS; off <<= 1) {
    int v = (t >= off) ? start[t - off] : 0;
    __syncthreads();
    start[t] += v;
    __syncthreads();
  }
  int excl = start[t] - hist[t];
  cur[t] = excl;

  int row = b * SBROWS + t;
  if (row < NNODES) {
    rs[row] = s + excl;
    re[row] = s + excl + hist[t];
  }
  __syncthreads();

  if (!ovf) {
    // scatter into LDS staging (strip row bits), then sequential writeback
#pragma unroll
    for (int k = 0; k < P2_K; ++k) {
      int idx = t + k * P2_THREADS;
      if (idx < n) {
        unsigned key = (unsigned)q[k];
        int pos = atomicAdd(&cur[key >> COLBITS], 1);
        out[pos] = ((q[k] >> 32) << 32) | (key & CMASK);
      }
    }
    __syncthreads();
    for (int j = t; j < n; j += P2_THREADS) pairs[s + j] = out[j];
  } else {
    for (int j = t; j < n; j += P2_THREADS) {
      ull p = slack[ovf_base + j];
      unsigned key = (unsigned)p;
      int pos = atomicAdd(&cur[key >> COLBITS], 1);
      pairs[s + pos] = ((p >> 32) << 32) | (key & CMASK);
    }
  }
}

// e0 (two split f32 tables) -> packed bf16 table (row = 64 bf16 = 128 B).
__global__ void conv_e16(const float4* __restrict__ user4,
                         const float4* __restrict__ item4,
                         uint2* __restrict__ E) {
  const int n4 = NNODES * EMB / 4;
  const int u4 = NUSERS * EMB / 4;
  int i = blockIdx.x * blockDim.x + threadIdx.x;
  if (i >= n4) return;
  float4 a = (i < u4) ? user4[i] : item4[i - u4];
  E[i] = make_uint2(pk2(a.x, a.y), pk2(a.z, a.w));
}

// ---------------- fused SpMM over bf16 table ----------------
// dest[r] = scale * (e0[r] + sum val * T[col]);  T bf16[NNODES][64], acc f32.
// 8 rows/wave x 8 lanes/row x uint4 (8 bf16 = 16 B per lane).
template <bool FINAL>
__global__ __launch_bounds__(256) void spmm_bf16(
    const int* __restrict__ rs, const int* __restrict__ re,
    const ull* __restrict__ pq, const ushort* __restrict__ T,
    const float* __restrict__ user_emb, const float* __restrict__ item_emb,
    void* __restrict__ dest, float scale) {
  const int lane = threadIdx.x & 63;
  const int sub  = lane >> 3;   // row-group 0..7 within the wave
  const int l4   = lane & 7;    // uint4 index within the bf16 row
  const int wid  = (int)((blockIdx.x * blockDim.x + threadIdx.x) >> 6);
  const int r = wid * 8 + sub;
  if (r >= NNODES) return;
  const int s = rs[r];
  const int e = re[r];
  const uint4* __restrict__ T4 = (const uint4*)T;

  float4 aL0 = make_float4(0.f, 0.f, 0.f, 0.f);
  float4 aH0 = make_float4(0.f, 0.f, 0.f, 0.f);
  float4 aL1 = make_float4(0.f, 0.f, 0.f, 0.f);
  float4 aH1 = make_float4(0.f, 0.f, 0.f, 0.f);

  auto fma8 = [&](float4& L, float4& H, float v, uint4 z) {
    L.x = fmaf(v, blo(z.x), L.x); L.y = fmaf(v, bhi(z.x), L.y);
    L.z = fmaf(v, blo(z.y), L.z); L.w = fmaf(v, bhi(z.y), L.w);
    H.x = fmaf(v, blo(z.z), H.x); H.y = fmaf(v, bhi(z.z), H.y);
    H.z = fmaf(v, blo(z.w), H.z); H.w = fmaf(v, bhi(z.w), H.w);
  };

  int i = s;
  for (; i + 3 < e; i += 4) {
    ull q0 = __builtin_nontemporal_load(&pq[i + 0]);
    ull q1 = __builtin_nontemporal_load(&pq[i + 1]);
    ull q2 = __builtin_nontemporal_load(&pq[i + 2]);
    ull q3 = __builtin_nontemporal_load(&pq[i + 3]);
    uint4 z0 = T4[(size_t)(unsigned)q0 * 8 + l4];
    uint4 z1 = T4[(size_t)(unsigned)q1 * 8 + l4];
    uint4 z2 = T4[(size_t)(unsigned)q2 * 8 + l4];
    uint4 z3 = T4[(size_t)(unsigned)q3 * 8 + l4];
    float v0 = __uint_as_float((unsigned)(q0 >> 32));
    float v1 = __uint_as_float((unsigned)(q1 >> 32));
    float v2 = __uint_as_float((unsigned)(q2 >> 32));
    float v3 = __uint_as_float((unsigned)(q3 >> 32));
    fma8(aL0, aH0, v0, z0);
    fma8(aL1, aH1, v1, z1);
    fma8(aL0, aH0, v2, z2);
    fma8(aL1, aH1, v3, z3);
  }
  for (; i < e; ++i) {
    ull q = __builtin_nontemporal_load(&pq[i]);
    uint4 z = T4[(size_t)(unsigned)q * 8 + l4];
    float v = __uint_as_float((unsigned)(q >> 32));
    fma8(aL0, aH0, v, z);
  }

  float4 aL, aH;
  aL.x = aL0.x + aL1.x; aL.y = aL0.y + aL1.y;
  aL.z = aL0.z + aL1.z; aL.w = aL0.w + aL1.w;
  aH.x = aH0.x + aH1.x; aH.y = aH0.y + aH1.y;
  aH.z = aH0.z + aH1.z; aH.w = aH0.w + aH1.w;

  const ull* e0p = (r < NUSERS)
      ? (const ull*)(user_emb + (size_t)r * EMB)
      : (const ull*)(item_emb + (size_t)(r - NUSERS) * EMB);
  ull eq0 = __builtin_nontemporal_load(&e0p[l4 * 4 + 0]);
  ull eq1 = __builtin_nontemporal_load(&e0p[l4 * 4 + 1]);
  ull eq2 = __builtin_nontemporal_load(&e0p[l4 * 4 + 2]);
  ull eq3 = __builtin_nontemporal_load(&e0p[l4 * 4 + 3]);
  float e0, e1, e2, e3, e4, e5, e6, e7;
  e0 = __uint_as_float((unsigned)eq0); e1 = __uint_as_float((unsigned)(eq0 >> 32));
  e2 = __uint_as_float((unsigned)eq1); e3 = __uint_as_float((unsigned)(eq1 >> 32));
  e4 = __uint_as_float((unsigned)eq2); e5 = __uint_as_float((unsigned)(eq2 >> 32));
  e6 = __uint_as_float((unsigned)eq3); e7 = __uint_as_float((unsigned)(eq3 >> 32));

  if (FINAL) {
    float4 oL, oH;
    oL.x = scale * (e0 + aL.x); oL.y = scale * (e1 + aL.y);
    oL.z = scale * (e2 + aL.z); oL.w = scale * (e3 + aL.w);
    oH.x = scale * (e4 + aH.x); oH.y = scale * (e5 + aH.y);
    oH.z = scale * (e6 + aH.z); oH.w = scale * (e7 + aH.w);
    float4* d4 = (float4*)dest;
    d4[(size_t)r * 16 + l4 * 2 + 0] = oL;
    d4[(size_t)r * 16 + l4 * 2 + 1] = oH;
  } else {
    uint4 ob;
    ob.x = pk2(e0 + aL.x, e1 + aL.y);
    ob.y = pk2(e2 + aL.z, e3 + aL.w);
    ob.z = pk2(e4 + aH.x, e5 + aH.y);
    ob.w = pk2(e6 + aH.z, e7 + aH.w);
    ((uint4*)dest)[(size_t)r * 8 + l4] = ob;
  }
}

// ---------------- fallback (atomic path, correct for any ws size) ----------------

__global__ void spmm_atomic(const float* __restrict__ vals,
                            const int* __restrict__ rows,
                            const int* __restrict__ cols,
                            const float* __restrict__ user_emb,
                            const float* __restrict__ item_emb,
                            const float* __restrict__ prev, int nnz,
                            float* __restrict__ y) {
  const int lane = threadIdx.x & 63;
  int wave = (int)((blockIdx.x * blockDim.x + threadIdx.x) >> 6);
  const int nwaves = (int)((gridDim.x * blockDim.x) >> 6);
  for (int nz = wave; nz < nnz; nz += nwaves) {
    float v = vals[nz];
    int r = rows[nz];
    int c = cols[nz];
    float xv = (c < NUSERS) ? user_emb[(size_t)c * EMB + lane]
                            : item_emb[(size_t)(c - NUSERS) * EMB + lane];
    if (prev) xv += prev[(size_t)c * EMB + lane];
    atomicAdd(&y[(size_t)r * EMB + lane], v * xv);
  }
}

__global__ void finalize_kernel(const float4* __restrict__ user4,
                                const float4* __restrict__ item4,
                                float4* __restrict__ X4) {
  const int n4 = NNODES * EMB / 4;
  const int u4 = NUSERS * EMB / 4;
  int i = blockIdx.x * blockDim.x + threadIdx.x;
  if (i >= n4) return;
  float4 a = (i < u4) ? user4[i] : item4[i - u4];
  float4 b = X4[i];
  b.x = 0.25f * (a.x + b.x);
  b.y = 0.25f * (a.y + b.y);
  b.z = 0.25f * (a.z + b.z);
  b.w = 0.25f * (a.w + b.w);
  X4[i] = b;
}

// ---------------- launch ----------------

extern "C" void kernel_launch(void* const* d_in, const int* in_sizes, int n_in,
                              void* d_out, int out_size, void* d_ws, size_t ws_size,
                              hipStream_t stream) {
  const float* user_emb = (const float*)d_in[0];
  const float* item_emb = (const float*)d_in[1];
  const float* vals     = (const float*)d_in[2];
  const int*   rows     = (const int*)d_in[3];
  const int*   cols     = (const int*)d_in[4];
  const int nnz = in_sizes[2];
  float* W = (float*)d_out;

  const float4* user4 = (const float4*)user_emb;
  const float4* item4 = (const float4*)item_emb;

  const int ntiles = (nnz + TILE - 1) / TILE;

  const size_t bfBytes   = (size_t)NNODES * EMB * 2;                        // 64 MB
  const size_t embBytes  = (size_t)NNODES * EMB * sizeof(float);            // 128 MB (fallback)
  const size_t pairBytes = ((size_t)nnz + SLACK_PAIRS) * sizeof(ull);       // ~82 MB
  const size_t rsBytes   = ((size_t)NNODES * 4 + 255) & ~(size_t)255;       // 2 MB
  const size_t reBytes   = rsBytes;
  const size_t ptrBytes  = ((size_t)(NSB + 1) * 4 + 255) & ~(size_t)255;
  const size_t curBytes  = ((size_t)NSB * 4 + 255) & ~(size_t)255;
  const size_t cntBytes  = ((size_t)NSB * 4 + 255) & ~(size_t)255;
  const size_t matBytes  = (((size_t)ntiles * NSB * 4) + 255) & ~(size_t)255; // ~5.5 MB
  const size_t ovfBytes  = 256;
  const size_t need = 2 * bfBytes + pairBytes + rsBytes + reBytes + ptrBytes +
                      curBytes + cntBytes + matBytes + ovfBytes;

  dim3 blk(256);

  if (ws_size < need) {  // safety fallback: atomic path (128 MB ws)
    float* Y = (float*)d_ws;
    hipMemsetAsync(W, 0, embBytes, stream);
    hipMemsetAsync(Y, 0, embBytes, stream);
    dim3 grid(4096);
    spmm_atomic<<<grid, blk, 0, stream>>>(vals, rows, cols, user_emb, item_emb, nullptr, nnz, W);
    spmm_atomic<<<grid, blk, 0, stream>>>(vals, rows, cols, user_emb, item_emb, W, nnz, Y);
    hipMemsetAsync(W, 0, embBytes, stream);
    spmm_atomic<<<grid, blk, 0, stream>>>(vals, rows, cols, user_emb, item_emb, Y, nnz, W);
    const int n4 = NNODES * EMB / 4;
    finalize_kernel<<<(n4 + 255) / 256, blk, 0, stream>>>(user4, item4, (float4*)W);
    return;
  }

  char* ws = (char*)d_ws;
  ushort* bfA   = (ushort*)ws; ws += bfBytes;
  ushort* bfB   = (ushort*)ws; ws += bfBytes;
  ull*   pairs  = (ull*)ws;    ws += pairBytes;
  int*   rsArr  = (int*)ws;    ws += rsBytes;
  int*   reArr  = (int*)ws;    ws += reBytes;
  int*   bptr   = (int*)ws;    ws += ptrBytes;
  int*   cursor = (int*)ws;    ws += curBytes;
  int*   counts = (int*)ws;    ws += cntBytes;
  int*   cntmat = (int*)ws;    ws += matBytes;
  int*   ovf    = (int*)ws;

  // --- deterministic two-level scan preprocessing ---
  hipMemsetAsync(counts, 0, (size_t)NSB * 4, stream);
  hipMemsetAsync(ovf, 0, 4, stream);
  hist_sb<<<256, blk, 0, stream>>>(rows, nnz, counts);
  scan_buckets<<<1, 512, 0, stream>>>(counts, bptr, cursor, NSB, nnz);
  tile_hist<<<ntiles, blk, 0, stream>>>(rows, nnz, cntmat);
  col_base<<<(NSB + 63) / 64, 64, 0, stream>>>(cntmat, ntiles, bptr);
  scatter_sb<<<ntiles, blk, 0, stream>>>(rows, cols, vals, nnz, cntmat, pairs);
  finalize_sb<<<NSB, P2_THREADS, 0, stream>>>(bptr, pairs, rsArr, reArr, ovf, nnz);

  // --- bfA = bf16(e0) ---
  const int n4 = NNODES * EMB / 4;
  conv_e16<<<(n4 + 255) / 256, blk, 0, stream>>>(user4, item4, (uint2*)bfA);

  // --- 3 layers, Horner ping-pong over bf16 tables ---
  const int sgrid = NNODES / 32;  // 15625 blocks; 8 rows/wave, 32 rows/block
  spmm_bf16<false><<<sgrid, blk, 0, stream>>>(rsArr, reArr, pairs, bfA,
                                              user_emb, item_emb, bfB, 1.0f);
  spmm_bf16<false><<<sgrid, blk, 0, stream>>>(rsArr, reArr, pairs, bfB,
                                              user_emb, item_emb, bfA, 1.0f);
  spmm_bf16<true ><<<sgrid, blk, 0, stream>>>(rsArr, reArr, pairs, bfA,
                                              user_emb, item_emb, W, 0.25f);
}

// Round 8
// 1278.895 us; speedup vs baseline: 1.0427x; 1.0427x over previous
//
#include <hip/hip_runtime.h>

// LightGCN: out = 0.25*(e0 + S e0 + S^2 e0 + S^3 e0), S = 10M-nnz COO, N=500k, EMB=64.
// R7: two-pass aggregated scatter. 1849.7 us.
// R9: bf16 gather tables. 1324.6 us. spmm at fabric roofline (~6 TB/s L2-miss bytes).
// R10: deterministic scan prep: NEUTRAL (1333.6). Prep ~535us invariant across 3 scatter
//   designs -> not atomics, not finalize write-thrash. spmm_bf16 3x266us, FETCH 871MB.
// R11: byte-shaving, no new buffers (NOT YET BENCHED - R7 slot hit GPU timeout):
//   (a) e0 term from bf16 for L1/L2 via aliasing: L1 T=bfA E0=bfA dest=bfB;
//       L2 T=bfB E0=bfA dest=bfA (own-row read-before-write, no cross-thread hazard);
//       L3 T=bfA E0=f32 dest=W (final precision preserved). Saves 64MB/layer x2.
//   (b) hist_sb deleted; counts = column-sum of cntmat (tiny colsum kernel).
// Horner: L1: bfB = bf16(e0 + S bfA); L2: bfA = bf16(e0 + S bfB); L3: W = 0.25(e0f32 + S bfA).

#define NUSERS 100000
#define NNODES 500000
#define EMB 64
#define COLBITS 19
#define CMASK ((1u << COLBITS) - 1u)

#define SBBITS 9                                   // 512 rows per super-bucket
#define SBROWS (1 << SBBITS)
#define SBMASK (SBROWS - 1)
#define NSB ((NNODES + SBROWS - 1) / SBROWS)       // 977
#define TILE 7168                                  // pairs staged per block in pass 1
#define P2_THREADS 512
#define P2_CAP 12800                               // LDS staging cap (mean 10240, sd ~101)
#define P2_K 25                                    // ceil(P2_CAP / P2_THREADS)
#define SLACK_PAIRS 262144                         // pass-2 overflow staging (never hit)

typedef unsigned long long ull;

// f32 pair -> packed bf16x2 (round-to-nearest-even)
__device__ __forceinline__ unsigned pk2(float lo, float hi) {
  unsigned a = __float_as_uint(lo);
  unsigned b = __float_as_uint(hi);
  a = (a + 0x7fffu + ((a >> 16) & 1u)) >> 16;
  b = (b + 0x7fffu + ((b >> 16) & 1u)) & 0xffff0000u;
  return (a & 0xffffu) | b;
}
__device__ __forceinline__ float blo(unsigned u) { return __uint_as_float(u << 16); }
__device__ __forceinline__ float bhi(unsigned u) { return __uint_as_float(u & 0xffff0000u); }

// ---------------- preprocessing ----------------

// Single-block exclusive scan of counts[n] (n <= 4096), 512 threads x 8.
__global__ void scan_buckets(const int* __restrict__ counts,
                             int* __restrict__ bptr, int n, int nnz) {
  __shared__ int s[512];
  const int t = threadIdx.x;
  const int base = t * 8;
  int e[8];
  int tsum = 0;
#pragma unroll
  for (int j = 0; j < 8; ++j) {
    e[j] = (base + j < n) ? counts[base + j] : 0;
    tsum += e[j];
  }
  s[t] = tsum;
  __syncthreads();
  for (int off = 1; off < 512; off <<= 1) {
    int v = (t >= off) ? s[t - off] : 0;
    __syncthreads();
    s[t] += v;
    __syncthreads();
  }
  int run = s[t] - tsum;
#pragma unroll
  for (int j = 0; j < 8; ++j) {
    if (base + j < n) bptr[base + j] = run;
    run += e[j];
  }
  if (t == 511) bptr[n] = nnz;
}

// Per-tile per-SB histogram -> cnt[t * NSB + sb] (coalesced row writes).
__global__ __launch_bounds__(256) void tile_hist(const int* __restrict__ rows, int nnz,
                                                 int* __restrict__ cntmat) {
  __shared__ int h[NSB];
  const int t = threadIdx.x;
  const int tile0 = blockIdx.x * TILE;
  const int tileN = min(TILE, nnz - tile0);
  if (tileN <= 0) return;
  for (int i = t; i < NSB; i += 256) h[i] = 0;
  __syncthreads();
  for (int i = t; i < tileN; i += 256) atomicAdd(&h[rows[tile0 + i] >> SBBITS], 1);
  __syncthreads();
  int* row = cntmat + (size_t)blockIdx.x * NSB;
  for (int i = t; i < NSB; i += 256) row[i] = h[i];
}

// counts[sb] = sum_t cntmat[t][sb]. 2D grid: x = sb-chunk (256 wide), y = tile-chunk.
__global__ void colsum(const int* __restrict__ A, int ntiles, int tchunk,
                       int* __restrict__ counts) {
  int sb = blockIdx.x * 256 + threadIdx.x;
  if (sb >= NSB) return;
  int t0 = blockIdx.y * tchunk;
  int t1 = min(t0 + tchunk, ntiles);
  int sum = 0;
  for (int t = t0; t < t1; ++t) sum += A[(size_t)t * NSB + sb];
  if (sum) atomicAdd(&counts[sb], sum);
}

// Convert per-tile counts into exact global bases, in place:
// A[t][sb] := bptr[sb] + sum_{t'<t} A[t'][sb].  One thread per SB column,
// software-pipelined depth-8 (loads coalesced across the 64 lanes of a wave).
__global__ void col_base(int* __restrict__ A, int ntiles,
                         const int* __restrict__ bptr) {
  int sb = blockIdx.x * 64 + threadIdx.x;
  if (sb >= NSB) return;
  int run = bptr[sb];
  int t = 0;
  if (ntiles >= 16) {
    int b0 = A[(size_t)0 * NSB + sb], b1 = A[(size_t)1 * NSB + sb];
    int b2 = A[(size_t)2 * NSB + sb], b3 = A[(size_t)3 * NSB + sb];
    int b4 = A[(size_t)4 * NSB + sb], b5 = A[(size_t)5 * NSB + sb];
    int b6 = A[(size_t)6 * NSB + sb], b7 = A[(size_t)7 * NSB + sb];
    for (; t + 16 <= ntiles; t += 8) {
      int n0 = A[(size_t)(t + 8) * NSB + sb],  n1 = A[(size_t)(t + 9) * NSB + sb];
      int n2 = A[(size_t)(t + 10) * NSB + sb], n3 = A[(size_t)(t + 11) * NSB + sb];
      int n4 = A[(size_t)(t + 12) * NSB + sb], n5 = A[(size_t)(t + 13) * NSB + sb];
      int n6 = A[(size_t)(t + 14) * NSB + sb], n7 = A[(size_t)(t + 15) * NSB + sb];
      A[(size_t)(t + 0) * NSB + sb] = run; run += b0;
      A[(size_t)(t + 1) * NSB + sb] = run; run += b1;
      A[(size_t)(t + 2) * NSB + sb] = run; run += b2;
      A[(size_t)(t + 3) * NSB + sb] = run; run += b3;
      A[(size_t)(t + 4) * NSB + sb] = run; run += b4;
      A[(size_t)(t + 5) * NSB + sb] = run; run += b5;
      A[(size_t)(t + 6) * NSB + sb] = run; run += b6;
      A[(size_t)(t + 7) * NSB + sb] = run; run += b7;
      b0 = n0; b1 = n1; b2 = n2; b3 = n3;
      b4 = n4; b5 = n5; b6 = n6; b7 = n7;
    }
    A[(size_t)(t + 0) * NSB + sb] = run; run += b0;
    A[(size_t)(t + 1) * NSB + sb] = run; run += b1;
    A[(size_t)(t + 2) * NSB + sb] = run; run += b2;
    A[(size_t)(t + 3) * NSB + sb] = run; run += b3;
    A[(size_t)(t + 4) * NSB + sb] = run; run += b4;
    A[(size_t)(t + 5) * NSB + sb] = run; run += b5;
    A[(size_t)(t + 6) * NSB + sb] = run; run += b6;
    A[(size_t)(t + 7) * NSB + sb] = run; run += b7;
    t += 8;
  }
  for (; t < ntiles; ++t) {
    size_t i = (size_t)t * NSB + sb;
    int c = A[i];
    A[i] = run;
    run += c;
  }
}

// Pass 1: LDS-aggregated scatter into NSB super-bucket regions at deterministic
// bases (no global atomics). key = (row&511)<<19 | col, val alongside.
__global__ __launch_bounds__(256) void scatter_sb(
    const int* __restrict__ rows, const int* __restrict__ cols,
    const float* __restrict__ vals, int nnz,
    const int* __restrict__ basemat, ull* __restrict__ pairs) {
  __shared__ ull stg[TILE];                    // 56 KiB
  __shared__ ushort sbid[TILE];                // 14 KiB
  __shared__ int cnt[NSB];                     // 3.9 KiB
  __shared__ int start[NSB];                   // 3.9 KiB
  __shared__ int ssc[256];                     // 1 KiB
  const int t = threadIdx.x;
  const int tile0 = blockIdx.x * TILE;
  const int tileN = min(TILE, nnz - tile0);
  if (tileN <= 0) return;

  for (int i = t; i < NSB; i += 256) cnt[i] = 0;
  __syncthreads();

  // phase A: read rows, histogram by SB (rows kept in registers)
  int rr[TILE / 256];
#pragma unroll
  for (int k = 0; k < TILE / 256; ++k) {
    int idx = tile0 + t + k * 256;
    rr[k] = (idx < nnz) ? rows[idx] : -1;
    if (rr[k] >= 0) atomicAdd(&cnt[rr[k] >> SBBITS], 1);
  }
  __syncthreads();

  // exclusive scan of cnt -> start (4 entries/thread, Hillis-Steele over 256)
  {
    int c[4];
    int tsum = 0;
#pragma unroll
    for (int j = 0; j < 4; ++j) {
      int i = t * 4 + j;
      c[j] = (i < NSB) ? cnt[i] : 0;
      tsum += c[j];
    }
    ssc[t] = tsum;
    __syncthreads();
    for (int off = 1; off < 256; off <<= 1) {
      int v = (t >= off) ? ssc[t - off] : 0;
      __syncthreads();
      ssc[t] += v;
      __syncthreads();
    }
    int run = ssc[t] - tsum;
#pragma unroll
    for (int j = 0; j < 4; ++j) {
      int i = t * 4 + j;
      if (i < NSB) start[i] = run;
      run += c[j];
    }
  }
  __syncthreads();
  for (int i = t; i < NSB; i += 256) cnt[i] = 0;
  __syncthreads();

  // phase B: read cols/vals, stage pairs grouped by SB in LDS (+ sbid tag)
#pragma unroll
  for (int k = 0; k < TILE / 256; ++k) {
    int idx = tile0 + t + k * 256;
    if (idx < nnz) {
      int r = rr[k];
      int sb = r >> SBBITS;
      unsigned key = ((unsigned)(r & SBMASK) << COLBITS) | (unsigned)cols[idx];
      ull p = ((ull)__float_as_uint(vals[idx]) << 32) | key;
      int j = start[sb] + atomicAdd(&cnt[sb], 1);
      stg[j] = p;
      sbid[j] = (ushort)sb;
    }
  }
  __syncthreads();

  // phase C: write staged pairs to deterministic global bases; consecutive j ->
  // same SB -> coalesced runs.
  const int* __restrict__ baserow = basemat + (size_t)blockIdx.x * NSB;
  for (int j = t; j < tileN; j += 256) {
    int sb = sbid[j];
    pairs[baserow[sb] + (j - start[sb])] = stg[j];
  }
}

// Pass 2: per-SB row grouping. Loads region into registers, counting sort by row,
// stages sorted result in LDS, writes back SEQUENTIALLY. rs/re per row.
__global__ __launch_bounds__(P2_THREADS) void finalize_sb(
    const int* __restrict__ bptr, ull* __restrict__ pairs,
    int* __restrict__ rs, int* __restrict__ re,
    int* __restrict__ ovf_alloc, int nnz) {
  __shared__ int hist[SBROWS];
  __shared__ int start[SBROWS];
  __shared__ int cur[SBROWS];
  __shared__ ull out[P2_CAP];                  // 100 KiB
  __shared__ int ovf_base;
  const int b = blockIdx.x;
  const int t = threadIdx.x;
  const int s = bptr[b];
  const int n = bptr[b + 1] - s;
  const bool ovf = (n > P2_CAP);

  hist[t] = 0;
  ull* __restrict__ slack = pairs + nnz;
  if (ovf && t == 0) ovf_base = atomicAdd(ovf_alloc, n);
  __syncthreads();

  ull q[P2_K];
  if (!ovf) {
#pragma unroll
    for (int k = 0; k < P2_K; ++k) {
      int idx = t + k * P2_THREADS;
      if (idx < n) {
        q[k] = pairs[s + idx];
        atomicAdd(&hist[(unsigned)q[k] >> COLBITS], 1);
      }
    }
  } else {
    for (int j = t; j < n; j += P2_THREADS) slack[ovf_base + j] = pairs[s + j];
    __syncthreads();
    for (int j = t; j < n; j += P2_THREADS)
      atomicAdd(&hist[(unsigned)slack[ovf_base + j] >> COLBITS], 1);
  }
  __syncthreads();

  start[t] = hist[t];
  __syncthreads();
  for (int off = 1; off < SBROWS; off <<= 1) {
    int v = (t >= off) ? start[t - off] : 0;
    __syncthreads();
    start[t] += v;
    __syncthreads();
  }
  int excl = start[t] - hist[t];
  cur[t] = excl;

  int row = b * SBROWS + t;
  if (row < NNODES) {
    rs[row] = s + excl;
    re[row] = s + excl + hist[t];
  }
  __syncthreads();

  if (!ovf) {
    // scatter into LDS staging (strip row bits), then sequential writeback
#pragma unroll
    for (int k = 0; k < P2_K; ++k) {
      int idx = t + k * P2_THREADS;
      if (idx < n) {
        unsigned key = (unsigned)q[k];
        int pos = atomicAdd(&cur[key >> COLBITS], 1);
        out[pos] = ((q[k] >> 32) << 32) | (key & CMASK);
      }
    }
    __syncthreads();
    for (int j = t; j < n; j += P2_THREADS) pairs[s + j] = out[j];
  } else {
    for (int j = t; j < n; j += P2_THREADS) {
      ull p = slack[ovf_base + j];
      unsigned key = (unsigned)p;
      int pos = atomicAdd(&cur[key >> COLBITS], 1);
      pairs[s + pos] = ((p >> 32) << 32) | (key & CMASK);
    }
  }
}

// e0 (two split f32 tables) -> packed bf16 table (row = 64 bf16 = 128 B).
__global__ void conv_e16(const float4* __restrict__ user4,
                         const float4* __restrict__ item4,
                         uint2* __restrict__ E) {
  const int n4 = NNODES * EMB / 4;
  const int u4 = NUSERS * EMB / 4;
  int i = blockIdx.x * blockDim.x + threadIdx.x;
  if (i >= n4) return;
  float4 a = (i < u4) ? user4[i] : item4[i - u4];
  E[i] = make_uint2(pk2(a.x, a.y), pk2(a.z, a.w));
}

// ---------------- fused SpMM over bf16 table ----------------
// dest[r] = scale * (e0[r] + sum val * T[col]);  T bf16[NNODES][64], acc f32.
// 8 rows/wave x 8 lanes/row x uint4 (8 bf16 = 16 B per lane).
// Non-FINAL: e0 term read from bf16 table E0bf (may alias T or dest: only the
// own row of dest is read, before it is written). FINAL: e0 from f32 tables.
template <bool FINAL>
__global__ __launch_bounds__(256) void spmm_bf16(
    const int* __restrict__ rs, const int* __restrict__ re,
    const ull* __restrict__ pq, const ushort* __restrict__ T,
    const ushort* __restrict__ E0bf,
    const float* __restrict__ user_emb, const float* __restrict__ item_emb,
    void* __restrict__ dest, float scale) {
  const int lane = threadIdx.x & 63;
  const int sub  = lane >> 3;   // row-group 0..7 within the wave
  const int l4   = lane & 7;    // uint4 index within the bf16 row
  const int wid  = (int)((blockIdx.x * blockDim.x + threadIdx.x) >> 6);
  const int r = wid * 8 + sub;
  if (r >= NNODES) return;
  const int s = rs[r];
  const int e = re[r];
  const uint4* __restrict__ T4 = (const uint4*)T;

  float4 aL0 = make_float4(0.f, 0.f, 0.f, 0.f);
  float4 aH0 = make_float4(0.f, 0.f, 0.f, 0.f);
  float4 aL1 = make_float4(0.f, 0.f, 0.f, 0.f);
  float4 aH1 = make_float4(0.f, 0.f, 0.f, 0.f);

  auto fma8 = [&](float4& L, float4& H, float v, uint4 z) {
    L.x = fmaf(v, blo(z.x), L.x); L.y = fmaf(v, bhi(z.x), L.y);
    L.z = fmaf(v, blo(z.y), L.z); L.w = fmaf(v, bhi(z.y), L.w);
    H.x = fmaf(v, blo(z.z), H.x); H.y = fmaf(v, bhi(z.z), H.y);
    H.z = fmaf(v, blo(z.w), H.z); H.w = fmaf(v, bhi(z.w), H.w);
  };

  int i = s;
  for (; i + 3 < e; i += 4) {
    ull q0 = __builtin_nontemporal_load(&pq[i + 0]);
    ull q1 = __builtin_nontemporal_load(&pq[i + 1]);
    ull q2 = __builtin_nontemporal_load(&pq[i + 2]);
    ull q3 = __builtin_nontemporal_load(&pq[i + 3]);
    uint4 z0 = T4[(size_t)(unsigned)q0 * 8 + l4];
    uint4 z1 = T4[(size_t)(unsigned)q1 * 8 + l4];
    uint4 z2 = T4[(size_t)(unsigned)q2 * 8 + l4];
    uint4 z3 = T4[(size_t)(unsigned)q3 * 8 + l4];
    float v0 = __uint_as_float((unsigned)(q0 >> 32));
    float v1 = __uint_as_float((unsigned)(q1 >> 32));
    float v2 = __uint_as_float((unsigned)(q2 >> 32));
    float v3 = __uint_as_float((unsigned)(q3 >> 32));
    fma8(aL0, aH0, v0, z0);
    fma8(aL1, aH1, v1, z1);
    fma8(aL0, aH0, v2, z2);
    fma8(aL1, aH1, v3, z3);
  }
  for (; i < e; ++i) {
    ull q = __builtin_nontemporal_load(&pq[i]);
    uint4 z = T4[(size_t)(unsigned)q * 8 + l4];
    float v = __uint_as_float((unsigned)(q >> 32));
    fma8(aL0, aH0, v, z);
  }

  float4 aL, aH;
  aL.x = aL0.x + aL1.x; aL.y = aL0.y + aL1.y;
  aL.z = aL0.z + aL1.z; aL.w = aL0.w + aL1.w;
  aH.x = aH0.x + aH1.x; aH.y = aH0.y + aH1.y;
  aH.z = aH0.z + aH1.z; aH.w = aH0.w + aH1.w;

  float e0, e1, e2, e3, e4, e5, e6, e7;
  if (FINAL) {
    const ull* e0p = (r < NUSERS)
        ? (const ull*)(user_emb + (size_t)r * EMB)
        : (const ull*)(item_emb + (size_t)(r - NUSERS) * EMB);
    ull eq0 = __builtin_nontemporal_load(&e0p[l4 * 4 + 0]);
    ull eq1 = __builtin_nontemporal_load(&e0p[l4 * 4 + 1]);
    ull eq2 = __builtin_nontemporal_load(&e0p[l4 * 4 + 2]);
    ull eq3 = __builtin_nontemporal_load(&e0p[l4 * 4 + 3]);
    e0 = __uint_as_float((unsigned)eq0); e1 = __uint_as_float((unsigned)(eq0 >> 32));
    e2 = __uint_as_float((unsigned)eq1); e3 = __uint_as_float((unsigned)(eq1 >> 32));
    e4 = __uint_as_float((unsigned)eq2); e5 = __uint_as_float((unsigned)(eq2 >> 32));
    e6 = __uint_as_float((unsigned)eq3); e7 = __uint_as_float((unsigned)(eq3 >> 32));
  } else {
    uint4 ue = ((const uint4*)E0bf)[(size_t)r * 8 + l4];
    e0 = blo(ue.x); e1 = bhi(ue.x);
    e2 = blo(ue.y); e3 = bhi(ue.y);
    e4 = blo(ue.z); e5 = bhi(ue.z);
    e6 = blo(ue.w); e7 = bhi(ue.w);
  }

  if (FINAL) {
    float4 oL, oH;
    oL.x = scale * (e0 + aL.x); oL.y = scale * (e1 + aL.y);
    oL.z = scale * (e2 + aL.z); oL.w = scale * (e3 + aL.w);
    oH.x = scale * (e4 + aH.x); oH.y = scale * (e5 + aH.y);
    oH.z = scale * (e6 + aH.z); oH.w = scale * (e7 + aH.w);
    float4* d4 = (float4*)dest;
    d4[(size_t)r * 16 + l4 * 2 + 0] = oL;
    d4[(size_t)r * 16 + l4 * 2 + 1] = oH;
  } else {
    uint4 ob;
    ob.x = pk2(e0 + aL.x, e1 + aL.y);
    ob.y = pk2(e2 + aL.z, e3 + aL.w);
    ob.z = pk2(e4 + aH.x, e5 + aH.y);
    ob.w = pk2(e6 + aH.z, e7 + aH.w);
    ((uint4*)dest)[(size_t)r * 8 + l4] = ob;
  }
}

// ---------------- fallback (atomic path, correct for any ws size) ----------------

__global__ void spmm_atomic(const float* __restrict__ vals,
                            const int* __restrict__ rows,
                            const int* __restrict__ cols,
                            const float* __restrict__ user_emb,
                            const float* __restrict__ item_emb,
                            const float* __restrict__ prev, int nnz,
                            float* __restrict__ y) {
  const int lane = threadIdx.x & 63;
  int wave = (int)((blockIdx.x * blockDim.x + threadIdx.x) >> 6);
  const int nwaves = (int)((gridDim.x * blockDim.x) >> 6);
  for (int nz = wave; nz < nnz; nz += nwaves) {
    float v = vals[nz];
    int r = rows[nz];
    int c = cols[nz];
    float xv = (c < NUSERS) ? user_emb[(size_t)c * EMB + lane]
                            : item_emb[(size_t)(c - NUSERS) * EMB + lane];
    if (prev) xv += prev[(size_t)c * EMB + lane];
    atomicAdd(&y[(size_t)r * EMB + lane], v * xv);
  }
}

__global__ void finalize_kernel(const float4* __restrict__ user4,
                                const float4* __restrict__ item4,
                                float4* __restrict__ X4) {
  const int n4 = NNODES * EMB / 4;
  const int u4 = NUSERS * EMB / 4;
  int i = blockIdx.x * blockDim.x + threadIdx.x;
  if (i >= n4) return;
  float4 a = (i < u4) ? user4[i] : item4[i - u4];
  float4 b = X4[i];
  b.x = 0.25f * (a.x + b.x);
  b.y = 0.25f * (a.y + b.y);
  b.z = 0.25f * (a.z + b.z);
  b.w = 0.25f * (a.w + b.w);
  X4[i] = b;
}

// ---------------- launch ----------------

extern "C" void kernel_launch(void* const* d_in, const int* in_sizes, int n_in,
                              void* d_out, int out_size, void* d_ws, size_t ws_size,
                              hipStream_t stream) {
  const float* user_emb = (const float*)d_in[0];
  const float* item_emb = (const float*)d_in[1];
  const float* vals     = (const float*)d_in[2];
  const int*   rows     = (const int*)d_in[3];
  const int*   cols     = (const int*)d_in[4];
  const int nnz = in_sizes[2];
  float* W = (float*)d_out;

  const float4* user4 = (const float4*)user_emb;
  const float4* item4 = (const float4*)item_emb;

  const int ntiles = (nnz + TILE - 1) / TILE;

  const size_t bfBytes   = (size_t)NNODES * EMB * 2;                        // 64 MB
  const size_t embBytes  = (size_t)NNODES * EMB * sizeof(float);            // 128 MB (fallback)
  const size_t pairBytes = ((size_t)nnz + SLACK_PAIRS) * sizeof(ull);       // ~82 MB
  const size_t rsBytes   = ((size_t)NNODES * 4 + 255) & ~(size_t)255;       // 2 MB
  const size_t reBytes   = rsBytes;
  const size_t ptrBytes  = ((size_t)(NSB + 1) * 4 + 255) & ~(size_t)255;
  const size_t cntBytes  = ((size_t)NSB * 4 + 255) & ~(size_t)255;
  const size_t matBytes  = (((size_t)ntiles * NSB * 4) + 255) & ~(size_t)255; // ~5.5 MB
  const size_t ovfBytes  = 256;
  const size_t need = 2 * bfBytes + pairBytes + rsBytes + reBytes + ptrBytes +
                      cntBytes + matBytes + ovfBytes;

  dim3 blk(256);

  if (ws_size < need) {  // safety fallback: atomic path (128 MB ws)
    float* Y = (float*)d_ws;
    hipMemsetAsync(W, 0, embBytes, stream);
    hipMemsetAsync(Y, 0, embBytes, stream);
    dim3 grid(4096);
    spmm_atomic<<<grid, blk, 0, stream>>>(vals, rows, cols, user_emb, item_emb, nullptr, nnz, W);
    spmm_atomic<<<grid, blk, 0, stream>>>(vals, rows, cols, user_emb, item_emb, W, nnz, Y);
    hipMemsetAsync(W, 0, embBytes, stream);
    spmm_atomic<<<grid, blk, 0, stream>>>(vals, rows, cols, user_emb, item_emb, Y, nnz, W);
    const int n4 = NNODES * EMB / 4;
    finalize_kernel<<<(n4 + 255) / 256, blk, 0, stream>>>(user4, item4, (float4*)W);
    return;
  }

  char* ws = (char*)d_ws;
  ushort* bfA   = (ushort*)ws; ws += bfBytes;
  ushort* bfB   = (ushort*)ws; ws += bfBytes;
  ull*   pairs  = (ull*)ws;    ws += pairBytes;
  int*   rsArr  = (int*)ws;    ws += rsBytes;
  int*   reArr  = (int*)ws;    ws += reBytes;
  int*   bptr   = (int*)ws;    ws += ptrBytes;
  int*   counts = (int*)ws;    ws += cntBytes;
  int*   cntmat = (int*)ws;    ws += matBytes;
  int*   ovf    = (int*)ws;

  // --- deterministic two-level scan preprocessing (hist_sb deleted: counts from cntmat) ---
  hipMemsetAsync(counts, 0, (size_t)NSB * 4, stream);
  hipMemsetAsync(ovf, 0, 4, stream);
  tile_hist<<<ntiles, blk, 0, stream>>>(rows, nnz, cntmat);
  {
    const int tchunk = (ntiles + 15) / 16;
    dim3 g((NSB + 255) / 256, 16);
    colsum<<<g, blk, 0, stream>>>(cntmat, ntiles, tchunk, counts);
  }
  scan_buckets<<<1, 512, 0, stream>>>(counts, bptr, NSB, nnz);
  col_base<<<(NSB + 63) / 64, 64, 0, stream>>>(cntmat, ntiles, bptr);
  scatter_sb<<<ntiles, blk, 0, stream>>>(rows, cols, vals, nnz, cntmat, pairs);
  finalize_sb<<<NSB, P2_THREADS, 0, stream>>>(bptr, pairs, rsArr, reArr, ovf, nnz);

  // --- bfA = bf16(e0) ---
  const int n4 = NNODES * EMB / 4;
  conv_e16<<<(n4 + 255) / 256, blk, 0, stream>>>(user4, item4, (uint2*)bfA);

  // --- 3 layers, Horner ping-pong; e0 term bf16 for L1/L2 (aliased), f32 for final ---
  const int sgrid = NNODES / 32;  // 15625 blocks; 8 rows/wave, 32 rows/block
  spmm_bf16<false><<<sgrid, blk, 0, stream>>>(rsArr, reArr, pairs, bfA, bfA,
                                              user_emb, item_emb, bfB, 1.0f);
  spmm_bf16<false><<<sgrid, blk, 0, stream>>>(rsArr, reArr, pairs, bfB, bfA,
                                              user_emb, item_emb, bfA, 1.0f);
  spmm_bf16<true ><<<sgrid, blk, 0, stream>>>(rsArr, reArr, pairs, bfA, nullptr,
                                              user_emb, item_emb, W, 0.25f);
}